// Round 1
// baseline (913.321 us; speedup 1.0000x reference)
//
#include <hip/hip_runtime.h>
#include <math.h>

// TGV-2 PDHG denoising, B=2, H=W=256, T=128.
// State layout (SoA, f32, N=131072 each):
//   u        -> d_out (read-modify-write per-pixel, no cross-thread hazard)
//   ws: ub, v1, v2, vb1, vb2, p1, p2, q11, q22, q12  (10 arrays, 5.24 MB)
// Two kernels per iteration (dual update, then primal update), 257 launches
// total, all graph-capturable (no sync, no alloc).

namespace {

constexpr int kN = 2 * 256 * 256;
constexpr float kTau = 0.28867513459481287f;   // 1/sqrt(12), matches f32 ref
constexpr float kSigma = kTau;
constexpr float kInv1pTau = 1.0f / (1.0f + kTau);

__global__ __launch_bounds__(256) void init_kernel(
    const float* __restrict__ f, float* __restrict__ u, float* __restrict__ ub,
    float* __restrict__ v1, float* __restrict__ v2,
    float* __restrict__ vb1, float* __restrict__ vb2,
    float* __restrict__ p1, float* __restrict__ p2,
    float* __restrict__ q11, float* __restrict__ q22, float* __restrict__ q12) {
  int n = blockIdx.x * 256 + threadIdx.x;
  float fv = f[n];
  u[n] = fv;
  ub[n] = fv;
  v1[n] = 0.f; v2[n] = 0.f;
  vb1[n] = 0.f; vb2[n] = 0.f;
  p1[n] = 0.f; p2[n] = 0.f;
  q11[n] = 0.f; q22[n] = 0.f; q12[n] = 0.f;
}

// Phase 1: dual ascent + projections.
//   p = proj_{alpha1}(p + sigma*(grad(u_bar) - v_bar))
//   q = proj_{alpha0,w=(1,1,2)}(q + sigma*sym_grad(v_bar))
// axis=1 (H) stride = 256, axis=2 (W) stride = 1; image stride 65536.
__global__ __launch_bounds__(256) void dual_kernel(
    const float* __restrict__ rp, const float* __restrict__ ub,
    const float* __restrict__ vb1, const float* __restrict__ vb2,
    float* __restrict__ p1, float* __restrict__ p2,
    float* __restrict__ q11, float* __restrict__ q22,
    float* __restrict__ q12) {
  int n = blockIdx.x * 256 + threadIdx.x;
  int j = n & 255;
  int i = (n >> 8) & 255;
  bool hasD = (i < 255);  // has down neighbor along H (axis 1)
  bool hasR = (j < 255);  // has right neighbor along W (axis 2)

  float alpha0 = rp[0];
  float alpha1 = rp[1];

  float ub_c = ub[n];
  float ub_d = hasD ? ub[n + 256] : ub_c;  // fwd diff -> 0 at boundary
  float ub_r = hasR ? ub[n + 1] : ub_c;

  float vb1_c = vb1[n], vb2_c = vb2[n];
  float vb1_d = hasD ? vb1[n + 256] : vb1_c;
  float vb1_r = hasR ? vb1[n + 1] : vb1_c;
  float vb2_d = hasD ? vb2[n + 256] : vb2_c;
  float vb2_r = hasR ? vb2[n + 1] : vb2_c;

  // p update
  float pn1 = p1[n] + kSigma * ((ub_d - ub_c) - vb1_c);
  float pn2 = p2[n] + kSigma * ((ub_r - ub_c) - vb2_c);
  float nrm = sqrtf(pn1 * pn1 + pn2 * pn2);
  float s = fmaxf(1.0f, nrm / alpha1);
  p1[n] = pn1 / s;
  p2[n] = pn2 / s;

  // q update (e11, e22, e12)
  float e11 = vb1_d - vb1_c;
  float e22 = vb2_r - vb2_c;
  float e12 = 0.5f * ((vb1_r - vb1_c) + (vb2_d - vb2_c));
  float qn1 = q11[n] + kSigma * e11;
  float qn2 = q22[n] + kSigma * e22;
  float qn3 = q12[n] + kSigma * e12;
  nrm = sqrtf(qn1 * qn1 + qn2 * qn2 + 2.0f * qn3 * qn3);
  s = fmaxf(1.0f, nrm / alpha0);
  q11[n] = qn1 / s;
  q22[n] = qn2 / s;
  q12[n] = qn3 / s;
}

// Phase 2: primal descent + over-relaxation.
//   u_new = (u + tau*div(p) + tau*f)/(1+tau);  ub = 2u_new - u
//   v_new = v + tau*(p + sym_div(q));          vb = 2v_new - v
// bwd_div(x,ax)[i] = (i < last ? x[i] : 0) - (i > 0 ? x[i-1] : 0)
__global__ __launch_bounds__(256) void primal_kernel(
    const float* __restrict__ f, float* __restrict__ u, float* __restrict__ ub,
    float* __restrict__ v1, float* __restrict__ v2,
    float* __restrict__ vb1, float* __restrict__ vb2,
    const float* __restrict__ p1, const float* __restrict__ p2,
    const float* __restrict__ q11, const float* __restrict__ q22,
    const float* __restrict__ q12) {
  int n = blockIdx.x * 256 + threadIdx.x;
  int j = n & 255;
  int i = (n >> 8) & 255;
  bool hasD = (i < 255), hasR = (j < 255);
  bool hasU = (i > 0), hasL = (j > 0);

  float p1c = p1[n], p2c = p2[n];
  float divp = (hasD ? p1c : 0.f) - (hasU ? p1[n - 256] : 0.f) +
               (hasR ? p2c : 0.f) - (hasL ? p2[n - 1] : 0.f);
  float uo = u[n];
  float un = (uo + kTau * divp + kTau * f[n]) * kInv1pTau;
  u[n] = un;
  ub[n] = 2.f * un - uo;

  float q11c = q11[n], q22c = q22[n], q12c = q12[n];
  float c1 = (hasD ? q11c : 0.f) - (hasU ? q11[n - 256] : 0.f) +
             (hasR ? q12c : 0.f) - (hasL ? q12[n - 1] : 0.f);
  float c2 = (hasD ? q12c : 0.f) - (hasU ? q12[n - 256] : 0.f) +
             (hasR ? q22c : 0.f) - (hasL ? q22[n - 1] : 0.f);
  float v1o = v1[n], v2o = v2[n];
  float v1n = v1o + kTau * (p1c + c1);
  float v2n = v2o + kTau * (p2c + c2);
  v1[n] = v1n;
  v2[n] = v2n;
  vb1[n] = 2.f * v1n - v1o;
  vb2[n] = 2.f * v2n - v2o;
}

}  // namespace

extern "C" void kernel_launch(void* const* d_in, const int* in_sizes, int n_in,
                              void* d_out, int out_size, void* d_ws,
                              size_t ws_size, hipStream_t stream) {
  const float* f = (const float*)d_in[0];
  const float* rp = (const float*)d_in[1];  // [alpha0, alpha1]
  // d_in[2] is T; fixed at 128 by the problem setup (host must know trip count
  // for graph capture, and kernel_launch must do identical work every call).

  float* u = (float*)d_out;
  float* w = (float*)d_ws;
  float* ub = w + 0 * kN;
  float* v1 = w + 1 * kN;
  float* v2 = w + 2 * kN;
  float* vb1 = w + 3 * kN;
  float* vb2 = w + 4 * kN;
  float* p1 = w + 5 * kN;
  float* p2 = w + 6 * kN;
  float* q11 = w + 7 * kN;
  float* q22 = w + 8 * kN;
  float* q12 = w + 9 * kN;

  dim3 grid(kN / 256), block(256);
  hipLaunchKernelGGL(init_kernel, grid, block, 0, stream, f, u, ub, v1, v2,
                     vb1, vb2, p1, p2, q11, q22, q12);
  for (int t = 0; t < 128; ++t) {
    hipLaunchKernelGGL(dual_kernel, grid, block, 0, stream, rp, ub, vb1, vb2,
                       p1, p2, q11, q22, q12);
    hipLaunchKernelGGL(primal_kernel, grid, block, 0, stream, f, u, ub, v1, v2,
                       vb1, vb2, p1, p2, q11, q22, q12);
  }
}

// Round 2
// 428.966 us; speedup vs baseline: 2.1291x; 2.1291x over previous
//
#include <hip/hip_runtime.h>
#include <math.h>

// TGV-2 PDHG, B=2, H=W=256, T=128.
// Temporal-blocked (trapezoid) kernel: each launch advances k=8 iterations.
// Block = one 32x32 tile + halo 8 => 48x48 region. 576 threads, each owns a
// 1x4 pixel strip; all 11 state fields + f live in registers; LDS holds full
// region copies of {ub,vb1,vb2} (dual halos) and {p1,p2,q11,q22,q12} (primal
// halos), re-published each iteration. Garbage at the region rim creeps
// inward 1 px/iter (dual fwd-diff + primal bwd-div) so after 8 iters the
// central 32x32 is exact; only that interior is stored back.
// 17 launches total vs 257 in the 2-kernel-per-iteration version.

namespace {

constexpr int kN = 2 * 256 * 256;
constexpr float kTau = 0.28867513459481287f;  // 1/sqrt(12) (f32)
constexpr float kSigma = kTau;
constexpr float kInv1pTau = 1.0f / (1.0f + kTau);

constexpr int R = 48;           // region side
constexpr int A = R * R;        // 2304 floats per LDS array
constexpr int PAD = 64;         // rim-overread safety pads (front/back)
constexpr int TILE = 32;
constexpr int HALO = 8;         // = iterations per launch
constexpr int NTHREADS = R * (R / 4);  // 576 = 9 waves

__device__ __forceinline__ float4 ld4(const float* p) {
  return *reinterpret_cast<const float4*>(p);
}
__device__ __forceinline__ void st4v(float* p, const float* a) {
  float4 v;
  v.x = a[0]; v.y = a[1]; v.z = a[2]; v.w = a[3];
  *reinterpret_cast<float4*>(p) = v;
}
__device__ __forceinline__ float msel(bool m, float x) { return m ? x : 0.f; }

// ws layout: 10 arrays of kN floats: ub, v1, v2, vb1, vb2, p1, p2, q11, q22, q12
__global__ __launch_bounds__(256) void init_kernel(const float* __restrict__ f,
                                                   float* __restrict__ u,
                                                   float* __restrict__ ws) {
  int n = blockIdx.x * 256 + threadIdx.x;
  float fv = f[n];
  u[n] = fv;
  ws[n] = fv;  // ub = u0
#pragma unroll
  for (int i = 1; i < 10; ++i) ws[i * kN + n] = 0.f;
}

__global__ __launch_bounds__(NTHREADS, 1) void tgv8_kernel(
    const float* __restrict__ f, const float* __restrict__ rp,
    float* __restrict__ ug, float* __restrict__ ws) {
  float* ubg = ws + 0 * kN;
  float* v1g = ws + 1 * kN;
  float* v2g = ws + 2 * kN;
  float* vb1g = ws + 3 * kN;
  float* vb2g = ws + 4 * kN;
  float* p1g = ws + 5 * kN;
  float* p2g = ws + 6 * kN;
  float* q11g = ws + 7 * kN;
  float* q22g = ws + 8 * kN;
  float* q12g = ws + 9 * kN;

  __shared__ __align__(16) float smem[PAD + 8 * A + PAD];
  float* ubS = smem + PAD;
  float* vb1S = ubS + A;
  float* vb2S = vb1S + A;
  float* p1S = vb2S + A;
  float* p2S = p1S + A;
  float* q11S = p2S + A;
  float* q22S = q11S + A;
  float* q12S = q22S + A;

  const int tid = threadIdx.x;
  const int r = tid / 12;      // region row 0..47
  const int c = (tid % 12) * 4;  // region col (float4-aligned)
  const int rc = r * R + c;

  const int gi = blockIdx.y * TILE + r - HALO;  // global row (may be OOB)
  const int gj = blockIdx.x * TILE + c - HALO;  // global col (group all-in/out)
  const bool inImg = ((unsigned)gi < 256u) && ((unsigned)gj < 256u);
  const int base = blockIdx.z * 65536 + gi * 256 + gj;

  const float alpha0 = rp[0];
  const float alpha1 = rp[1];

  // image-boundary masks (global coords; garbage positions don't matter)
  const bool hasD = (gi != 255);
  const bool hasU = (gi != 0);

  float u_[4], ub_[4], v1_[4], v2_[4], vb1_[4], vb2_[4];
  float p1_[4], p2_[4], q11_[4], q22_[4], q12_[4], f_[4];

  if (inImg) {
#define LOADV(dst, src)                                  \
  {                                                      \
    float4 t_ = ld4((src) + base);                       \
    dst[0] = t_.x; dst[1] = t_.y; dst[2] = t_.z; dst[3] = t_.w; \
  }
    LOADV(f_, f)
    LOADV(u_, ug)
    LOADV(ub_, ubg)
    LOADV(v1_, v1g)
    LOADV(v2_, v2g)
    LOADV(vb1_, vb1g)
    LOADV(vb2_, vb2g)
    LOADV(p1_, p1g)
    LOADV(p2_, p2g)
    LOADV(q11_, q11g)
    LOADV(q22_, q22g)
    LOADV(q12_, q12g)
#undef LOADV
  } else {
#pragma unroll
    for (int e = 0; e < 4; ++e) {
      f_[e] = 0.f; u_[e] = 0.f; ub_[e] = 0.f;
      v1_[e] = 0.f; v2_[e] = 0.f; vb1_[e] = 0.f; vb2_[e] = 0.f;
      p1_[e] = 0.f; p2_[e] = 0.f; q11_[e] = 0.f; q22_[e] = 0.f; q12_[e] = 0.f;
    }
  }

  for (int t = 0; t < HALO; ++t) {
    // ---- publish dual halos (ub, vb) ----
    st4v(ubS + rc, ub_);
    st4v(vb1S + rc, vb1_);
    st4v(vb2S + rc, vb2_);
    __syncthreads();

    // ---- dual ascent + projections (updates p,q in registers) ----
    const float ubX = ubS[rc + 4];
    const float vb1X = vb1S[rc + 4];
    const float vb2X = vb2S[rc + 4];
    float4 td;
    td = ld4(ubS + rc + R);
    const float ubD[4] = {td.x, td.y, td.z, td.w};
    td = ld4(vb1S + rc + R);
    const float vb1D[4] = {td.x, td.y, td.z, td.w};
    td = ld4(vb2S + rc + R);
    const float vb2D[4] = {td.x, td.y, td.z, td.w};

#pragma unroll
    for (int e = 0; e < 4; ++e) {
      const bool hR = (gj + e != 255);
      const float ubr = (e < 3) ? ub_[e + 1] : ubX;
      const float vb1r = (e < 3) ? vb1_[e + 1] : vb1X;
      const float vb2r = (e < 3) ? vb2_[e + 1] : vb2X;

      const float du1 = msel(hasD, ubD[e] - ub_[e]);  // fwd diff axis1 (H)
      const float du2 = msel(hR, ubr - ub_[e]);       // fwd diff axis2 (W)
      float pn1 = p1_[e] + kSigma * (du1 - vb1_[e]);
      float pn2 = p2_[e] + kSigma * (du2 - vb2_[e]);
      float nrm = sqrtf(pn1 * pn1 + pn2 * pn2);
      float sc = alpha1 * __builtin_amdgcn_rcpf(fmaxf(alpha1, nrm));
      p1_[e] = pn1 * sc;
      p2_[e] = pn2 * sc;

      const float e11 = msel(hasD, vb1D[e] - vb1_[e]);
      const float e22 = msel(hR, vb2r - vb2_[e]);
      const float e12 =
          0.5f * (msel(hR, vb1r - vb1_[e]) + msel(hasD, vb2D[e] - vb2_[e]));
      float qn1 = q11_[e] + kSigma * e11;
      float qn2 = q22_[e] + kSigma * e22;
      float qn3 = q12_[e] + kSigma * e12;
      nrm = sqrtf(qn1 * qn1 + qn2 * qn2 + 2.f * qn3 * qn3);
      sc = alpha0 * __builtin_amdgcn_rcpf(fmaxf(alpha0, nrm));
      q11_[e] = qn1 * sc;
      q22_[e] = qn2 * sc;
      q12_[e] = qn3 * sc;
    }

    // ---- publish primal halos (new p, q) ----
    st4v(p1S + rc, p1_);
    st4v(p2S + rc, p2_);
    st4v(q11S + rc, q11_);
    st4v(q22S + rc, q22_);
    st4v(q12S + rc, q12_);
    __syncthreads();

    // ---- primal descent + over-relaxation ----
    float4 tu;
    tu = ld4(p1S + rc - R);
    const float p1U[4] = {tu.x, tu.y, tu.z, tu.w};
    tu = ld4(q11S + rc - R);
    const float q11U[4] = {tu.x, tu.y, tu.z, tu.w};
    tu = ld4(q12S + rc - R);
    const float q12U[4] = {tu.x, tu.y, tu.z, tu.w};
    const float p2Lx = p2S[rc - 1];
    const float q22Lx = q22S[rc - 1];
    const float q12Lx = q12S[rc - 1];

#pragma unroll
    for (int e = 0; e < 4; ++e) {
      const bool hR = (gj + e != 255);
      const bool hL = (e == 0) ? (gj != 0) : true;
      const float p2l = (e == 0) ? p2Lx : p2_[e - 1];
      const float q22l = (e == 0) ? q22Lx : q22_[e - 1];
      const float q12l = (e == 0) ? q12Lx : q12_[e - 1];

      const float divp = msel(hasD, p1_[e]) - msel(hasU, p1U[e]) +
                         msel(hR, p2_[e]) - msel(hL, p2l);
      const float un = (u_[e] + kTau * divp + kTau * f_[e]) * kInv1pTau;
      ub_[e] = 2.f * un - u_[e];
      u_[e] = un;

      const float c1 = msel(hasD, q11_[e]) - msel(hasU, q11U[e]) +
                       msel(hR, q12_[e]) - msel(hL, q12l);
      const float c2 = msel(hasD, q12_[e]) - msel(hasU, q12U[e]) +
                       msel(hR, q22_[e]) - msel(hL, q22l);
      const float v1n = v1_[e] + kTau * (p1_[e] + c1);
      const float v2n = v2_[e] + kTau * (p2_[e] + c2);
      vb1_[e] = 2.f * v1n - v1_[e];
      v1_[e] = v1n;
      vb2_[e] = 2.f * v2n - v2_[e];
      v2_[e] = v2n;
    }
  }

  // ---- store interior 32x32 (exact after 8 iters) ----
  if (r >= HALO && r < HALO + TILE && c >= HALO && c < HALO + TILE) {
    st4v(ug + base, u_);
    st4v(ubg + base, ub_);
    st4v(v1g + base, v1_);
    st4v(v2g + base, v2_);
    st4v(vb1g + base, vb1_);
    st4v(vb2g + base, vb2_);
    st4v(p1g + base, p1_);
    st4v(p2g + base, p2_);
    st4v(q11g + base, q11_);
    st4v(q22g + base, q22_);
    st4v(q12g + base, q12_);
  }
}

}  // namespace

extern "C" void kernel_launch(void* const* d_in, const int* in_sizes, int n_in,
                              void* d_out, int out_size, void* d_ws,
                              size_t ws_size, hipStream_t stream) {
  const float* f = (const float*)d_in[0];
  const float* rp = (const float*)d_in[1];  // [alpha0, alpha1]
  // d_in[2] is T = 128 (fixed; trip count must be static for graph capture).

  float* u = (float*)d_out;
  float* ws = (float*)d_ws;

  hipLaunchKernelGGL(init_kernel, dim3(kN / 256), dim3(256), 0, stream, f, u,
                     ws);
  dim3 grid(256 / TILE, 256 / TILE, 2);  // 8 x 8 x 2 = 128 blocks
  for (int t = 0; t < 128 / HALO; ++t) {  // 16 launches x 8 iterations
    hipLaunchKernelGGL(tgv8_kernel, grid, dim3(NTHREADS), 0, stream, f, rp, u,
                       ws);
  }
}

// Round 3
// 395.569 us; speedup vs baseline: 2.3089x; 1.0844x over previous
//
#include <hip/hip_runtime.h>
#include <math.h>

// TGV-2 PDHG, B=2, H=W=256, T=128.
// Temporal-blocked (trapezoid) kernel: each launch advances k=8 iterations.
// R3: 16x16 tile + halo 8 => 32x32 region, 512 blocks (2 per CU), 256 threads
// (4 waves). Two blocks per CU so one block's barrier drain overlaps the
// other's compute. All LDS traffic is aligned ds_read/write_b128 (row stride
// 32 words => linear bank pattern, conflict-free). Each thread owns a 1x4
// strip; all 11 state fields + f live in registers; LDS holds full region
// copies of {ub,vb1,vb2} (dual halos) and {p1,p2,q11,q22,q12} (primal halos).
// Garbage at the region rim creeps inward 1 px/iter, so after 8 iters the
// central 16x16 is exact; only the interior is stored back. 17 launches.

namespace {

constexpr int kN = 2 * 256 * 256;
constexpr float kTau = 0.28867513459481287f;  // 1/sqrt(12) (f32)
constexpr float kSigma = kTau;
constexpr float kInv1pTau = 1.0f / (1.0f + kTau);

constexpr int R = 32;           // region side
constexpr int A = R * R;        // 1024 floats per LDS array
constexpr int PAD = 64;         // rim-overread safety pads (front/back)
constexpr int TILE = 16;
constexpr int HALO = 8;         // = iterations per launch
constexpr int NTHREADS = R * (R / 4);  // 256 = 4 waves

__device__ __forceinline__ float4 ld4(const float* p) {
  return *reinterpret_cast<const float4*>(p);
}
__device__ __forceinline__ void st4v(float* p, const float* a) {
  float4 v;
  v.x = a[0]; v.y = a[1]; v.z = a[2]; v.w = a[3];
  *reinterpret_cast<float4*>(p) = v;
}
__device__ __forceinline__ float msel(bool m, float x) { return m ? x : 0.f; }

// ws layout: 10 arrays of kN floats: ub, v1, v2, vb1, vb2, p1, p2, q11, q22, q12
__global__ __launch_bounds__(256) void init_kernel(const float* __restrict__ f,
                                                   float* __restrict__ u,
                                                   float* __restrict__ ws) {
  int n = blockIdx.x * 256 + threadIdx.x;
  float fv = f[n];
  u[n] = fv;
  ws[n] = fv;  // ub = u0
#pragma unroll
  for (int i = 1; i < 10; ++i) ws[i * kN + n] = 0.f;
}

__global__ __launch_bounds__(NTHREADS, 2) void tgv8_kernel(
    const float* __restrict__ f, const float* __restrict__ rp,
    float* __restrict__ ug, float* __restrict__ ws) {
  float* ubg = ws + 0 * kN;
  float* v1g = ws + 1 * kN;
  float* v2g = ws + 2 * kN;
  float* vb1g = ws + 3 * kN;
  float* vb2g = ws + 4 * kN;
  float* p1g = ws + 5 * kN;
  float* p2g = ws + 6 * kN;
  float* q11g = ws + 7 * kN;
  float* q22g = ws + 8 * kN;
  float* q12g = ws + 9 * kN;

  __shared__ __align__(16) float smem[PAD + 8 * A + PAD];
  float* ubS = smem + PAD;
  float* vb1S = ubS + A;
  float* vb2S = vb1S + A;
  float* p1S = vb2S + A;
  float* p2S = p1S + A;
  float* q11S = p2S + A;
  float* q22S = q11S + A;
  float* q12S = q22S + A;

  const int tid = threadIdx.x;
  const int r = tid >> 3;         // region row 0..31
  const int c = (tid & 7) * 4;    // region col (float4-aligned)
  const int rc = r * R + c;

  const int gi = blockIdx.y * TILE + r - HALO;  // global row (may be OOB)
  const int gj = blockIdx.x * TILE + c - HALO;  // global col (float4 in/out)
  const bool inImg = ((unsigned)gi < 256u) && ((unsigned)gj < 256u);
  const int base = blockIdx.z * 65536 + gi * 256 + gj;

  const float alpha0 = rp[0];
  const float alpha1 = rp[1];

  // image-boundary masks (global coords; garbage positions don't matter)
  const bool hasD = (gi != 255);
  const bool hasU = (gi != 0);

  float u_[4], ub_[4], v1_[4], v2_[4], vb1_[4], vb2_[4];
  float p1_[4], p2_[4], q11_[4], q22_[4], q12_[4], f_[4];

  if (inImg) {
#define LOADV(dst, src)                                  \
  {                                                      \
    float4 t_ = ld4((src) + base);                       \
    dst[0] = t_.x; dst[1] = t_.y; dst[2] = t_.z; dst[3] = t_.w; \
  }
    LOADV(f_, f)
    LOADV(u_, ug)
    LOADV(ub_, ubg)
    LOADV(v1_, v1g)
    LOADV(v2_, v2g)
    LOADV(vb1_, vb1g)
    LOADV(vb2_, vb2g)
    LOADV(p1_, p1g)
    LOADV(p2_, p2g)
    LOADV(q11_, q11g)
    LOADV(q22_, q22g)
    LOADV(q12_, q12g)
#undef LOADV
  } else {
#pragma unroll
    for (int e = 0; e < 4; ++e) {
      f_[e] = 0.f; u_[e] = 0.f; ub_[e] = 0.f;
      v1_[e] = 0.f; v2_[e] = 0.f; vb1_[e] = 0.f; vb2_[e] = 0.f;
      p1_[e] = 0.f; p2_[e] = 0.f; q11_[e] = 0.f; q22_[e] = 0.f; q12_[e] = 0.f;
    }
  }

  for (int t = 0; t < HALO; ++t) {
    // ---- publish dual halos (ub, vb) ----
    st4v(ubS + rc, ub_);
    st4v(vb1S + rc, vb1_);
    st4v(vb2S + rc, vb2_);
    __syncthreads();

    // ---- dual ascent + projections (updates p,q in registers) ----
    const float ubX = ld4(ubS + rc + 4).x;    // right-edge neighbor, aligned
    const float vb1X = ld4(vb1S + rc + 4).x;
    const float vb2X = ld4(vb2S + rc + 4).x;
    float4 td;
    td = ld4(ubS + rc + R);
    const float ubD[4] = {td.x, td.y, td.z, td.w};
    td = ld4(vb1S + rc + R);
    const float vb1D[4] = {td.x, td.y, td.z, td.w};
    td = ld4(vb2S + rc + R);
    const float vb2D[4] = {td.x, td.y, td.z, td.w};

#pragma unroll
    for (int e = 0; e < 4; ++e) {
      const bool hR = (gj + e != 255);
      const float ubr = (e < 3) ? ub_[e + 1] : ubX;
      const float vb1r = (e < 3) ? vb1_[e + 1] : vb1X;
      const float vb2r = (e < 3) ? vb2_[e + 1] : vb2X;

      const float du1 = msel(hasD, ubD[e] - ub_[e]);  // fwd diff axis1 (H)
      const float du2 = msel(hR, ubr - ub_[e]);       // fwd diff axis2 (W)
      float pn1 = p1_[e] + kSigma * (du1 - vb1_[e]);
      float pn2 = p2_[e] + kSigma * (du2 - vb2_[e]);
      float nrm = sqrtf(pn1 * pn1 + pn2 * pn2);
      float sc = alpha1 * __builtin_amdgcn_rcpf(fmaxf(alpha1, nrm));
      p1_[e] = pn1 * sc;
      p2_[e] = pn2 * sc;

      const float e11 = msel(hasD, vb1D[e] - vb1_[e]);
      const float e22 = msel(hR, vb2r - vb2_[e]);
      const float e12 =
          0.5f * (msel(hR, vb1r - vb1_[e]) + msel(hasD, vb2D[e] - vb2_[e]));
      float qn1 = q11_[e] + kSigma * e11;
      float qn2 = q22_[e] + kSigma * e22;
      float qn3 = q12_[e] + kSigma * e12;
      nrm = sqrtf(qn1 * qn1 + qn2 * qn2 + 2.f * qn3 * qn3);
      sc = alpha0 * __builtin_amdgcn_rcpf(fmaxf(alpha0, nrm));
      q11_[e] = qn1 * sc;
      q22_[e] = qn2 * sc;
      q12_[e] = qn3 * sc;
    }

    // ---- publish primal halos (new p, q) ----
    st4v(p1S + rc, p1_);
    st4v(p2S + rc, p2_);
    st4v(q11S + rc, q11_);
    st4v(q22S + rc, q22_);
    st4v(q12S + rc, q12_);
    __syncthreads();

    // ---- primal descent + over-relaxation ----
    float4 tu;
    tu = ld4(p1S + rc - R);
    const float p1U[4] = {tu.x, tu.y, tu.z, tu.w};
    tu = ld4(q11S + rc - R);
    const float q11U[4] = {tu.x, tu.y, tu.z, tu.w};
    tu = ld4(q12S + rc - R);
    const float q12U[4] = {tu.x, tu.y, tu.z, tu.w};
    const float p2Lx = ld4(p2S + rc - 4).w;   // left-edge neighbor, aligned
    const float q22Lx = ld4(q22S + rc - 4).w;
    const float q12Lx = ld4(q12S + rc - 4).w;

#pragma unroll
    for (int e = 0; e < 4; ++e) {
      const bool hR = (gj + e != 255);
      const bool hL = (e == 0) ? (gj != 0) : true;
      const float p2l = (e == 0) ? p2Lx : p2_[e - 1];
      const float q22l = (e == 0) ? q22Lx : q22_[e - 1];
      const float q12l = (e == 0) ? q12Lx : q12_[e - 1];

      const float divp = msel(hasD, p1_[e]) - msel(hasU, p1U[e]) +
                         msel(hR, p2_[e]) - msel(hL, p2l);
      const float un = (u_[e] + kTau * divp + kTau * f_[e]) * kInv1pTau;
      ub_[e] = 2.f * un - u_[e];
      u_[e] = un;

      const float c1 = msel(hasD, q11_[e]) - msel(hasU, q11U[e]) +
                       msel(hR, q12_[e]) - msel(hL, q12l);
      const float c2 = msel(hasD, q12_[e]) - msel(hasU, q12U[e]) +
                       msel(hR, q22_[e]) - msel(hL, q22l);
      const float v1n = v1_[e] + kTau * (p1_[e] + c1);
      const float v2n = v2_[e] + kTau * (p2_[e] + c2);
      vb1_[e] = 2.f * v1n - v1_[e];
      v1_[e] = v1n;
      vb2_[e] = 2.f * v2n - v2_[e];
      v2_[e] = v2n;
    }
  }

  // ---- store interior 16x16 (exact after 8 iters) ----
  if (r >= HALO && r < HALO + TILE && c >= HALO && c < HALO + TILE) {
    st4v(ug + base, u_);
    st4v(ubg + base, ub_);
    st4v(v1g + base, v1_);
    st4v(v2g + base, v2_);
    st4v(vb1g + base, vb1_);
    st4v(vb2g + base, vb2_);
    st4v(p1g + base, p1_);
    st4v(p2g + base, p2_);
    st4v(q11g + base, q11_);
    st4v(q22g + base, q22_);
    st4v(q12g + base, q12_);
  }
}

}  // namespace

extern "C" void kernel_launch(void* const* d_in, const int* in_sizes, int n_in,
                              void* d_out, int out_size, void* d_ws,
                              size_t ws_size, hipStream_t stream) {
  const float* f = (const float*)d_in[0];
  const float* rp = (const float*)d_in[1];  // [alpha0, alpha1]
  // d_in[2] is T = 128 (fixed; trip count must be static for graph capture).

  float* u = (float*)d_out;
  float* ws = (float*)d_ws;

  hipLaunchKernelGGL(init_kernel, dim3(kN / 256), dim3(256), 0, stream, f, u,
                     ws);
  dim3 grid(256 / TILE, 256 / TILE, 2);  // 16 x 16 x 2 = 512 blocks, 2 per CU
  for (int t = 0; t < 128 / HALO; ++t) {  // 16 launches x 8 iterations
    hipLaunchKernelGGL(tgv8_kernel, grid, dim3(NTHREADS), 0, stream, f, rp, u,
                       ws);
  }
}